// Round 3
// baseline (4782.659 us; speedup 1.0000x reference)
//
#include <hip/hip_runtime.h>
#include <hip/hip_bf16.h>

#define DEV static __device__ __forceinline__

// ---------------------------------------------------------------------------
// Static device workspace (independent of harness ws_size).
// ---------------------------------------------------------------------------
__device__ float    g_stats[2576];     // 5 layers x 512 (sum, sumsq, scale, shift)
__device__ unsigned g_cnt[16];         // active-voxel counts per layer
__device__ float    g_y1[2097152];     // (2,32,32^3)
__device__ float    g_m1[65536];       // (2,32^3)
__device__ float    g_y2[524288];      // (2,64,16^3)
__device__ float    g_m2[8192];        // (2,16^3)
__device__ float    g_y3[131072];      // (2,128,8^3)
__device__ float    g_m3[1024];        // (2,8^3)
__device__ float    g_t1[1048576];     // (2,128,16^3)
__device__ float    g_mt1[8192];       // (2,16^3)
__device__ float    g_mt2[65536];      // (2,32^3)
__device__ float    g_t2[4194304];     // (2,64,32^3)

// ---------------------------------------------------------------------------
__global__ void zero_stats_kernel() {
    for (int i = threadIdx.x; i < 2576; i += 256) g_stats[i] = 0.f;
    if (threadIdx.x < 16) g_cnt[threadIdx.x] = 0u;
}

// ---------------------------------------------------------------------------
// mask dilation bodies
// ---------------------------------------------------------------------------
DEV void mask_down_body(const float* mprev, float* mout, unsigned* cnt,
                        int logDin, int logDo) {
    int Din = 1 << logDin, Do = 1 << logDo;
    int idx = blockIdx.x * 256 + threadIdx.x;
    int b = idx >> (3 * logDo), v = idx & ((1 << (3 * logDo)) - 1);
    int od = v >> (2 * logDo), rem = v & ((1 << (2 * logDo)) - 1);
    int oh = rem >> logDo, ow = rem & (Do - 1);
    const float* mp = mprev + ((size_t)b << (3 * logDin));
    float acc = 0.f;
    for (int kd = 0; kd < 4; kd++) {
        int id = 2 * od - 1 + kd;
        if ((unsigned)id >= (unsigned)Din) continue;
        for (int kh = 0; kh < 4; kh++) {
            int ih = 2 * oh - 1 + kh;
            if ((unsigned)ih >= (unsigned)Din) continue;
            const float* row = mp + ((size_t)id * Din + ih) * Din;
            for (int kw = 0; kw < 4; kw++) {
                int iw = 2 * ow - 1 + kw;
                if ((unsigned)iw < (unsigned)Din) acc += row[iw];
            }
        }
    }
    float mv = acc > 0.f ? 1.f : 0.f;
    mout[idx] = mv;
    if (mv > 0.f) atomicAdd(cnt, 1u);
}

DEV void mask_up_body(const float* mprev, float* mout, unsigned* cnt,
                      int logDin, int logDo) {
    int Din = 1 << logDin, Do = 1 << logDo;
    int idx = blockIdx.x * 256 + threadIdx.x;
    int b = idx >> (3 * logDo), v = idx & ((1 << (3 * logDo)) - 1);
    int od = v >> (2 * logDo), rem = v & ((1 << (2 * logDo)) - 1);
    int oh = rem >> logDo, ow = rem & (Do - 1);
    const float* mp = mprev + ((size_t)b << (3 * logDin));
    float acc = 0.f;
    for (int kd = 0; kd < 4; kd++) {
        int u = od + kd - 2; if (u < 0 || (u & 1)) continue;
        int id = u >> 1; if (id >= Din) continue;
        for (int kh = 0; kh < 4; kh++) {
            int uh = oh + kh - 2; if (uh < 0 || (uh & 1)) continue;
            int ih = uh >> 1; if (ih >= Din) continue;
            const float* row = mp + ((size_t)id * Din + ih) * Din;
            for (int kw = 0; kw < 4; kw++) {
                int uw = ow + kw - 2; if (uw < 0 || (uw & 1)) continue;
                int iw = uw >> 1; if (iw >= Din) continue;
                acc += row[iw];
            }
        }
    }
    float mv = acc > 0.f ? 1.f : 0.f;
    mout[idx] = mv;
    if (mv > 0.f) atomicAdd(cnt, 1u);
}

// mask1: reads fp32 input mask with >0.5 threshold, 64^3 -> 32^3
__global__ __launch_bounds__(256)
void mask1_kernel(const float* __restrict__ mask) {
    int idx = blockIdx.x * 256 + threadIdx.x;      // 2*32^3 = 65536
    int b = idx >> 15, v = idx & 0x7FFF;
    int od = v >> 10, rem = v & 1023;
    int oh = rem >> 5, ow = rem & 31;
    const float* mp = mask + ((size_t)b << 18);
    float acc = 0.f;
    for (int kd = 0; kd < 4; kd++) {
        int id = 2 * od - 1 + kd;
        if ((unsigned)id >= 64u) continue;
        for (int kh = 0; kh < 4; kh++) {
            int ih = 2 * oh - 1 + kh;
            if ((unsigned)ih >= 64u) continue;
            const float* row = mp + ((size_t)id * 64 + ih) * 64;
            for (int kw = 0; kw < 4; kw++) {
                int iw = 2 * ow - 1 + kw;
                if ((unsigned)iw < 64u && row[iw] > 0.5f) acc += 1.f;
            }
        }
    }
    float mv = acc > 0.f ? 1.f : 0.f;
    g_m1[idx] = mv;
    if (mv > 0.f) atomicAdd(&g_cnt[0], 1u);
}

__global__ __launch_bounds__(256) void mask2_kernel() { mask_down_body(g_m1, g_m2, &g_cnt[1], 5, 4); }
__global__ __launch_bounds__(256) void mask3_kernel() { mask_down_body(g_m2, g_m3, &g_cnt[2], 4, 3); }
__global__ __launch_bounds__(256) void mask4_kernel() { mask_up_body(g_m3, g_mt1, &g_cnt[3], 3, 4); }
__global__ __launch_bounds__(256) void mask5_kernel() { mask_up_body(g_mt1, g_mt2, &g_cnt[4], 4, 5); }

// ---------------------------------------------------------------------------
// epilogue: bias, mask, LeakyReLU, store, block-reduced sum/sumsq atomics
// ---------------------------------------------------------------------------
DEV void conv_epilogue(float acc, float biasv, float mv, float* ydst,
                       float* stats, int co) {
    float yv = (acc + biasv) * mv;
    yv = yv >= 0.f ? yv : 0.01f * yv;
    *ydst = yv;
    float s = yv, s2 = yv * yv;
#pragma unroll
    for (int off = 32; off; off >>= 1) {
        s += __shfl_down(s, off, 64);
        s2 += __shfl_down(s2, off, 64);
    }
    __shared__ float red[8];
    int lane = threadIdx.x & 63, wv = threadIdx.x >> 6;
    if (!lane) { red[wv] = s; red[4 + wv] = s2; }
    __syncthreads();
    if (!threadIdx.x) {
        atomicAdd(&stats[co],       red[0] + red[1] + red[2] + red[3]);
        atomicAdd(&stats[128 + co], red[4] + red[5] + red[6] + red[7]);
    }
}

// ---------------------------------------------------------------------------
// conv1 fused with input prep: x = feat * (mask>0.5), 4ch 64^3 -> 32ch 32^3
// grid (128, 32, 2)
// ---------------------------------------------------------------------------
__global__ __launch_bounds__(256)
void conv1_kernel(const float* __restrict__ feat,
                  const float* __restrict__ mask,
                  const float* __restrict__ w,
                  const float* __restrict__ bias) {
    __shared__ float Wsh[4 * 64];
    int co = blockIdx.y, b = blockIdx.z;
    if (threadIdx.x < 256) Wsh[threadIdx.x] = w[co * 256 + threadIdx.x];
    __syncthreads();

    int v = blockIdx.x * 256 + threadIdx.x;        // 32^3
    int od = v >> 10, rem = v & 1023;
    int oh = rem >> 5, ow = rem & 31;

    const float* mb = mask + ((size_t)b << 18);
    const float* fbp = feat + ((size_t)(b * 4) << 18);

    float acc = 0.f;
    for (int kd = 0; kd < 4; kd++) {
        int id = 2 * od - 1 + kd;
        if ((unsigned)id >= 64u) continue;
        for (int kh = 0; kh < 4; kh++) {
            int ih = 2 * oh - 1 + kh;
            if ((unsigned)ih >= 64u) continue;
            for (int kw = 0; kw < 4; kw++) {
                int iw = 2 * ow - 1 + kw;
                if ((unsigned)iw >= 64u) continue;
                int off = (id << 12) + (ih << 6) + iw;
                if (mb[off] > 0.5f) {
                    int kidx = (kd << 4) + (kh << 2) + kw;
                    float s = 0.f;
#pragma unroll
                    for (int ci = 0; ci < 4; ci++)
                        s = fmaf(fbp[(ci << 18) + off], Wsh[(ci << 6) + kidx], s);
                    acc += s;
                }
            }
        }
    }
    float mv = g_m1[((size_t)b << 15) + v];
    conv_epilogue(acc, bias[co], mv,
                  &g_y1[(((size_t)b * 32 + co) << 15) + v], g_stats + 0, co);
}

// ---------------------------------------------------------------------------
// generic down conv body (fp32 input from globals)
// ---------------------------------------------------------------------------
template <int CIN>
DEV void conv_down_body(const float* x, const float* w,
                        const float* bias, const float* m2,
                        float* y, float* stats, int logDin, int logDo) {
    __shared__ float Wsh[CIN * 64];
    int co = blockIdx.y, b = blockIdx.z, Cout = gridDim.y;
    for (int i = threadIdx.x; i < CIN * 64; i += 256) Wsh[i] = w[co * CIN * 64 + i];
    __syncthreads();

    int Din = 1 << logDin, Do = 1 << logDo;
    int DinSq = Din * Din, Dv3 = 1 << (3 * logDin);
    int v = blockIdx.x * 256 + threadIdx.x;
    int od = v >> (2 * logDo), rem = v & ((1 << (2 * logDo)) - 1);
    int oh = rem >> logDo, ow = rem & (Do - 1);

    int idl[4], kdl[4], nd = 0;
    for (int k = 0; k < 4; k++) { int id = 2 * od - 1 + k; if ((unsigned)id < (unsigned)Din) { idl[nd] = id; kdl[nd] = k << 4; nd++; } }
    int ihl[4], khl[4], nh = 0;
    for (int k = 0; k < 4; k++) { int ih = 2 * oh - 1 + k; if ((unsigned)ih < (unsigned)Din) { ihl[nh] = ih; khl[nh] = k << 2; nh++; } }
    int iwl[4], kwl[4], nw = 0;
    for (int k = 0; k < 4; k++) { int iw = 2 * ow - 1 + k; if ((unsigned)iw < (unsigned)Din) { iwl[nw] = iw; kwl[nw] = k; nw++; } }

    float acc = 0.f;
    const float* xb = x + ((size_t)(b * CIN) << (3 * logDin));
    for (int ci = 0; ci < CIN; ci++) {
        const float* xc = xb + (size_t)ci * Dv3;
        const float* Wc = Wsh + (ci << 6);
        for (int a = 0; a < nd; a++) {
            const float* xd = xc + (size_t)idl[a] * DinSq;
            const float* Wd = Wc + kdl[a];
            for (int h = 0; h < nh; h++) {
                const float* xh = xd + ihl[h] * Din;
                const float* Wh = Wd + khl[h];
                for (int wi = 0; wi < nw; wi++)
                    acc = fmaf(xh[iwl[wi]], Wh[kwl[wi]], acc);
            }
        }
    }
    float mv = m2[((size_t)b << (3 * logDo)) + v];
    conv_epilogue(acc, bias[co], mv,
                  &y[(((size_t)b * Cout + co) << (3 * logDo)) + v], stats, co);
}

// ---------------------------------------------------------------------------
// generic transpose conv body
// ---------------------------------------------------------------------------
template <int CIN>
DEV void conv_up_body(const float* x, const float* w,
                      const float* bias, const float* m2,
                      float* y, float* stats, int logDin, int logDo) {
    __shared__ float Wsh[CIN * 64];
    int co = blockIdx.y, b = blockIdx.z, Cout = gridDim.y;
    for (int i = threadIdx.x; i < CIN * 64; i += 256) Wsh[i] = w[co * CIN * 64 + i];
    __syncthreads();

    int Din = 1 << logDin, Do = 1 << logDo;
    int DinSq = Din * Din, Dv3 = 1 << (3 * logDin);
    int v = blockIdx.x * 256 + threadIdx.x;
    int od = v >> (2 * logDo), rem = v & ((1 << (2 * logDo)) - 1);
    int oh = rem >> logDo, ow = rem & (Do - 1);

    int idl[2], kdl[2], nd = 0;
    for (int k = 0; k < 4; k++) { int u = od + k - 2; if (u >= 0 && !(u & 1)) { int id = u >> 1; if (id < Din) { idl[nd] = id; kdl[nd] = (3 - k) << 4; nd++; } } }
    int ihl[2], khl[2], nh = 0;
    for (int k = 0; k < 4; k++) { int u = oh + k - 2; if (u >= 0 && !(u & 1)) { int ih = u >> 1; if (ih < Din) { ihl[nh] = ih; khl[nh] = (3 - k) << 2; nh++; } } }
    int iwl[2], kwl[2], nw = 0;
    for (int k = 0; k < 4; k++) { int u = ow + k - 2; if (u >= 0 && !(u & 1)) { int iw = u >> 1; if (iw < Din) { iwl[nw] = iw; kwl[nw] = 3 - k; nw++; } } }

    float acc = 0.f;
    const float* xb = x + ((size_t)(b * CIN) << (3 * logDin));
    for (int ci = 0; ci < CIN; ci++) {
        const float* xc = xb + (size_t)ci * Dv3;
        const float* Wc = Wsh + (ci << 6);
        for (int a = 0; a < nd; a++) {
            const float* xd = xc + (size_t)idl[a] * DinSq;
            const float* Wd = Wc + kdl[a];
            for (int h = 0; h < nh; h++) {
                const float* xh = xd + ihl[h] * Din;
                const float* Wh = Wd + khl[h];
                for (int wi = 0; wi < nw; wi++)
                    acc = fmaf(xh[iwl[wi]], Wh[kwl[wi]], acc);
            }
        }
    }
    float mv = m2[((size_t)b << (3 * logDo)) + v];
    conv_epilogue(acc, bias[co], mv,
                  &y[(((size_t)b * Cout + co) << (3 * logDo)) + v], stats, co);
}

__global__ __launch_bounds__(256)
void conv2_kernel(const float* w, const float* bias)
{ conv_down_body<32>(g_y1, w, bias, g_m2, g_y2, g_stats + 512, 5, 4); }

__global__ __launch_bounds__(256)
void conv3_kernel(const float* w, const float* bias)
{ conv_down_body<64>(g_y2, w, bias, g_m3, g_y3, g_stats + 1024, 4, 3); }

__global__ __launch_bounds__(256)
void conv4_kernel(const float* w, const float* bias)
{ conv_up_body<128>(g_y3, w, bias, g_mt1, g_t1, g_stats + 1536, 3, 4); }

__global__ __launch_bounds__(256)
void conv5_kernel(const float* w, const float* bias)
{ conv_up_body<128>(g_t1, w, bias, g_mt2, g_t2, g_stats + 2048, 4, 5); }

// ---------------------------------------------------------------------------
// stats finalize
// ---------------------------------------------------------------------------
DEV void finalize_body(float* stats, const unsigned* cnt,
                       const float* g, const float* be, int C) {
    int c = threadIdx.x;
    if (c >= C) return;
    unsigned cu = *cnt;
    float n = (float)(cu < 1u ? 1u : cu);
    float mean = stats[c] / n;
    float var = fmaxf(stats[128 + c] / n - mean * mean, 0.f);
    float rstd = rsqrtf(var + 1e-5f);
    float sc = g[c] * rstd;
    stats[256 + c] = sc;
    stats[384 + c] = be[c] - mean * sc;
}

__global__ void fin1_kernel(const float* g, const float* be) { finalize_body(g_stats + 0,    &g_cnt[0], g, be, 32); }
__global__ void fin2_kernel(const float* g, const float* be) { finalize_body(g_stats + 512,  &g_cnt[1], g, be, 64); }
__global__ void fin3_kernel(const float* g, const float* be) { finalize_body(g_stats + 1024, &g_cnt[2], g, be, 128); }
__global__ void fin4_kernel(const float* g, const float* be) { finalize_body(g_stats + 1536, &g_cnt[3], g, be, 128); }
__global__ void fin5_kernel(const float* g, const float* be) { finalize_body(g_stats + 2048, &g_cnt[4], g, be, 64); }

// ---------------------------------------------------------------------------
// BN apply
// ---------------------------------------------------------------------------
DEV void bn_body(float* y, const float* stats, const float* m2, int logC, int logDvox) {
    int idx = blockIdx.x * 256 + threadIdx.x;
    int v = idx & ((1 << logDvox) - 1);
    int c = (idx >> logDvox) & ((1 << logC) - 1);
    int b = idx >> (logDvox + logC);
    float mv = m2[((size_t)b << logDvox) + v];
    y[idx] = (y[idx] * stats[256 + c] + stats[384 + c]) * mv;
}

__global__ __launch_bounds__(256) void bn1_kernel() { bn_body(g_y1, g_stats + 0,    g_m1, 5, 15); }
__global__ __launch_bounds__(256) void bn2_kernel() { bn_body(g_y2, g_stats + 512,  g_m2, 6, 12); }
__global__ __launch_bounds__(256) void bn3_kernel() { bn_body(g_y3, g_stats + 1024, g_m3, 7, 9); }
__global__ __launch_bounds__(256) void bn4_kernel() { bn_body(g_t1, g_stats + 1536, g_mt1, 7, 12); }
__global__ __launch_bounds__(256) void bn5_kernel() { bn_body(g_t2, g_stats + 2048, g_mt2, 6, 15); }

// ---------------------------------------------------------------------------
// final dense 1x1x1 conv 64->32 @ 32^3, bias everywhere, fp32 out
// grid (128, 32, 2)
// ---------------------------------------------------------------------------
__global__ __launch_bounds__(256)
void final_conv_kernel(const float* __restrict__ fw,
                       const float* __restrict__ fb,
                       float* __restrict__ out) {
    __shared__ float W[64];
    int co = blockIdx.y, b = blockIdx.z;
    if (threadIdx.x < 64) W[threadIdx.x] = fw[co * 64 + threadIdx.x];
    __syncthreads();
    int v = blockIdx.x * 256 + threadIdx.x;
    float acc = fb[co];
    const float* xb = g_t2 + ((size_t)b * 64 << 15);
#pragma unroll 8
    for (int ci = 0; ci < 64; ci++) acc = fmaf(xb[((size_t)ci << 15) + v], W[ci], acc);
    out[(((size_t)b * 32 + co) << 15) + v] = acc;
}

// ---------------------------------------------------------------------------

extern "C" void kernel_launch(void* const* d_in, const int* in_sizes, int n_in,
                              void* d_out, int out_size, void* d_ws, size_t ws_size,
                              hipStream_t stream) {
    (void)in_sizes; (void)n_in; (void)out_size; (void)d_ws; (void)ws_size;
    const float* feat = (const float*)d_in[0];
    const float* mask = (const float*)d_in[1];
    const float* w1  = (const float*)d_in[2];
    const float* b1  = (const float*)d_in[3];
    const float* g1  = (const float*)d_in[4];
    const float* be1 = (const float*)d_in[5];
    const float* w2  = (const float*)d_in[6];
    const float* b2  = (const float*)d_in[7];
    const float* g2  = (const float*)d_in[8];
    const float* be2 = (const float*)d_in[9];
    const float* w3  = (const float*)d_in[10];
    const float* b3  = (const float*)d_in[11];
    const float* g3  = (const float*)d_in[12];
    const float* be3 = (const float*)d_in[13];
    const float* tw1 = (const float*)d_in[14];
    const float* tb1 = (const float*)d_in[15];
    const float* tg1 = (const float*)d_in[16];
    const float* tbe1= (const float*)d_in[17];
    const float* tw2 = (const float*)d_in[18];
    const float* tb2 = (const float*)d_in[19];
    const float* tg2 = (const float*)d_in[20];
    const float* tbe2= (const float*)d_in[21];
    const float* fw  = (const float*)d_in[22];
    const float* fb  = (const float*)d_in[23];

    zero_stats_kernel<<<1, 256, 0, stream>>>();

    // block 1: 4->32, 64^3 -> 32^3
    mask1_kernel<<<256, 256, 0, stream>>>(mask);
    conv1_kernel<<<dim3(128, 32, 2), 256, 0, stream>>>(feat, mask, w1, b1);
    fin1_kernel<<<1, 128, 0, stream>>>(g1, be1);
    bn1_kernel<<<8192, 256, 0, stream>>>();

    // block 2: 32->64, 32^3 -> 16^3
    mask2_kernel<<<32, 256, 0, stream>>>();
    conv2_kernel<<<dim3(16, 64, 2), 256, 0, stream>>>(w2, b2);
    fin2_kernel<<<1, 128, 0, stream>>>(g2, be2);
    bn2_kernel<<<2048, 256, 0, stream>>>();

    // block 3: 64->128, 16^3 -> 8^3
    mask3_kernel<<<4, 256, 0, stream>>>();
    conv3_kernel<<<dim3(2, 128, 2), 256, 0, stream>>>(w3, b3);
    fin3_kernel<<<1, 128, 0, stream>>>(g3, be3);
    bn3_kernel<<<512, 256, 0, stream>>>();

    // up block 1: 128->128, 8^3 -> 16^3
    mask4_kernel<<<32, 256, 0, stream>>>();
    conv4_kernel<<<dim3(16, 128, 2), 256, 0, stream>>>(tw1, tb1);
    fin4_kernel<<<1, 128, 0, stream>>>(tg1, tbe1);
    bn4_kernel<<<4096, 256, 0, stream>>>();

    // up block 2: 128->64, 16^3 -> 32^3
    mask5_kernel<<<256, 256, 0, stream>>>();
    conv5_kernel<<<dim3(128, 64, 2), 256, 0, stream>>>(tw2, tb2);
    fin5_kernel<<<1, 128, 0, stream>>>(tg2, tbe2);
    bn5_kernel<<<16384, 256, 0, stream>>>();

    // final dense 1x1x1 conv 64->32 @ 32^3
    final_conv_kernel<<<dim3(128, 32, 2), 256, 0, stream>>>(fw, fb, (float*)d_out);
}

// Round 4
// 811.401 us; speedup vs baseline: 5.8943x; 5.8943x over previous
//
#include <hip/hip_runtime.h>

#define DEV static __device__ __forceinline__

// ---------------------------------------------------------------------------
// Static device workspace
// ---------------------------------------------------------------------------
__device__ float    g_stats[2576];     // 5 layers x 512 (sum, sumsq, scale, shift)
__device__ unsigned g_cnt[16];
__device__ float    g_y1[2097152];     // (2,32,32^3)
__device__ float    g_m1[65536];       // (2,32^3)
__device__ float    g_y2[524288];      // (2,64,16^3)
__device__ float    g_m2[8192];       // (2,16^3)
__device__ float    g_y3[131072];     // (2,128,8^3)
__device__ float    g_m3[1024];       // (2,8^3)
__device__ float    g_t1[1048576];    // (2,128,16^3)
__device__ float    g_mt1[8192];      // (2,16^3)
__device__ float    g_mt2[65536];     // (2,32^3)
__device__ float    g_t2[4194304];    // (2,64,32^3)

// ---------------------------------------------------------------------------
__global__ void zero_stats_kernel() {
    for (int i = threadIdx.x; i < 2576; i += 256) g_stats[i] = 0.f;
    if (threadIdx.x < 16) g_cnt[threadIdx.x] = 0u;
}

// ---------------------------------------------------------------------------
// mask dilation kernels (cheap, unchanged from passing round)
// ---------------------------------------------------------------------------
DEV void mask_down_body(const float* mprev, float* mout, unsigned* cnt,
                        int logDin, int logDo) {
    int Din = 1 << logDin, Do = 1 << logDo;
    int idx = blockIdx.x * 256 + threadIdx.x;
    int b = idx >> (3 * logDo), v = idx & ((1 << (3 * logDo)) - 1);
    int od = v >> (2 * logDo), rem = v & ((1 << (2 * logDo)) - 1);
    int oh = rem >> logDo, ow = rem & (Do - 1);
    const float* mp = mprev + ((size_t)b << (3 * logDin));
    float acc = 0.f;
    for (int kd = 0; kd < 4; kd++) {
        int id = 2 * od - 1 + kd;
        if ((unsigned)id >= (unsigned)Din) continue;
        for (int kh = 0; kh < 4; kh++) {
            int ih = 2 * oh - 1 + kh;
            if ((unsigned)ih >= (unsigned)Din) continue;
            const float* row = mp + ((size_t)id * Din + ih) * Din;
            for (int kw = 0; kw < 4; kw++) {
                int iw = 2 * ow - 1 + kw;
                if ((unsigned)iw < (unsigned)Din) acc += row[iw];
            }
        }
    }
    float mv = acc > 0.f ? 1.f : 0.f;
    mout[idx] = mv;
    if (mv > 0.f) atomicAdd(cnt, 1u);
}

DEV void mask_up_body(const float* mprev, float* mout, unsigned* cnt,
                      int logDin, int logDo) {
    int Din = 1 << logDin, Do = 1 << logDo;
    int idx = blockIdx.x * 256 + threadIdx.x;
    int b = idx >> (3 * logDo), v = idx & ((1 << (3 * logDo)) - 1);
    int od = v >> (2 * logDo), rem = v & ((1 << (2 * logDo)) - 1);
    int oh = rem >> logDo, ow = rem & (Do - 1);
    const float* mp = mprev + ((size_t)b << (3 * logDin));
    float acc = 0.f;
    for (int kd = 0; kd < 4; kd++) {
        int u = od + kd - 2; if (u < 0 || (u & 1)) continue;
        int id = u >> 1; if (id >= Din) continue;
        for (int kh = 0; kh < 4; kh++) {
            int uh = oh + kh - 2; if (uh < 0 || (uh & 1)) continue;
            int ih = uh >> 1; if (ih >= Din) continue;
            const float* row = mp + ((size_t)id * Din + ih) * Din;
            for (int kw = 0; kw < 4; kw++) {
                int uw = ow + kw - 2; if (uw < 0 || (uw & 1)) continue;
                int iw = uw >> 1; if (iw >= Din) continue;
                acc += row[iw];
            }
        }
    }
    float mv = acc > 0.f ? 1.f : 0.f;
    mout[idx] = mv;
    if (mv > 0.f) atomicAdd(cnt, 1u);
}

__global__ __launch_bounds__(256)
void mask1_kernel(const float* __restrict__ mask) {
    int idx = blockIdx.x * 256 + threadIdx.x;      // 2*32^3
    int b = idx >> 15, v = idx & 0x7FFF;
    int od = v >> 10, rem = v & 1023;
    int oh = rem >> 5, ow = rem & 31;
    const float* mp = mask + ((size_t)b << 18);
    float acc = 0.f;
    for (int kd = 0; kd < 4; kd++) {
        int id = 2 * od - 1 + kd;
        if ((unsigned)id >= 64u) continue;
        for (int kh = 0; kh < 4; kh++) {
            int ih = 2 * oh - 1 + kh;
            if ((unsigned)ih >= 64u) continue;
            const float* row = mp + ((size_t)id * 64 + ih) * 64;
            for (int kw = 0; kw < 4; kw++) {
                int iw = 2 * ow - 1 + kw;
                if ((unsigned)iw < 64u && row[iw] > 0.5f) acc += 1.f;
            }
        }
    }
    float mv = acc > 0.f ? 1.f : 0.f;
    g_m1[idx] = mv;
    if (mv > 0.f) atomicAdd(&g_cnt[0], 1u);
}

__global__ __launch_bounds__(256) void mask2_kernel() { mask_down_body(g_m1, g_m2, &g_cnt[1], 5, 4); }
__global__ __launch_bounds__(256) void mask3_kernel() { mask_down_body(g_m2, g_m3, &g_cnt[2], 4, 3); }
__global__ __launch_bounds__(256) void mask4_kernel() { mask_up_body(g_m3, g_mt1, &g_cnt[3], 3, 4); }
__global__ __launch_bounds__(256) void mask5_kernel() { mask_up_body(g_mt1, g_mt2, &g_cnt[4], 4, 5); }

// ---------------------------------------------------------------------------
// implicit-GEMM conv body.
// MODE: 0 = down conv (k4 s2 p1), 1 = transpose conv (per-parity, blockIdx.z),
//       2 = final 1x1x1 dense, 3 = down conv fused with mask*feat prep.
// Block: 256 threads as 16(tc: co dim) x 16(tv: vox dim); thread computes
// (MT/16) co x (NT/16) vox accumulators. A/B tiles staged in LDS, KT=32.
// ---------------------------------------------------------------------------
template<int MODE, int MT, int NT, int CIN, int COUT, int LOGDI, int LOGDO>
DEV void gemm_body(const float* __restrict__ x, const float* __restrict__ rawm,
                   const float* __restrict__ w, const float* __restrict__ bias,
                   const float* __restrict__ m2, float* __restrict__ y,
                   float* __restrict__ stats) {
    constexpr int KT = 32;
    constexpr int K  = (MODE == 1) ? CIN * 8 : ((MODE == 2) ? CIN : CIN * 64);
    constexpr int MR = MT / 16, VR = NT / 16;
    constexpr int EA = KT * MT / 256, EB = KT * NT / 256;
    constexpr int LMT = (MT == 64) ? 6 : 5, LNT = (NT == 64) ? 6 : 5;
    constexpr int Din = 1 << LOGDI, Do = 1 << LOGDO;

    __shared__ float As[KT * MT];
    __shared__ float Bs[KT * NT];

    const int tid = threadIdx.x, tc = tid & 15, tv = tid >> 4;
    const int bx = blockIdx.x, by = blockIdx.y;
    int pd = 0, ph = 0, pw = 0;
    if (MODE == 1) { int p = blockIdx.z; pd = (p >> 2) & 1; ph = (p >> 1) & 1; pw = p & 1; }

    float acc[MR][VR];
#pragma unroll
    for (int r = 0; r < MR; r++)
#pragma unroll
        for (int c = 0; c < VR; c++) acc[r][c] = 0.f;

    for (int kt = 0; kt < K; kt += KT) {
        __syncthreads();
        // ---- stage A: weights [KT][MT]
#pragma unroll
        for (int e = 0; e < EA; e++) {
            int j = tid * EA + e;
            int kk = j >> LMT, m = j & (MT - 1);
            int kg = kt + kk;
            int co = by * MT + m;
            float val;
            if constexpr (MODE == 1) {
                int ci = kg >> 3, t = kg & 7;
                int td = (t >> 2) & 1, th = (t >> 1) & 1, tw = t & 1;
                int kd = 3 - pd - 2 * td, kh = 3 - ph - 2 * th, kw = 3 - pw - 2 * tw;
                val = w[((size_t)co * CIN + ci) * 64 + kd * 16 + kh * 4 + kw];
            } else if constexpr (MODE == 2) {
                val = w[co * CIN + kg];
            } else {
                val = w[(size_t)co * (CIN * 64) + kg];
            }
            As[kk * MT + m] = val;
        }
        // ---- stage B: im2col gather [KT][NT]
#pragma unroll
        for (int e = 0; e < EB; e++) {
            int j = tid * EB + e;
            int kk = j >> LNT, n = j & (NT - 1);
            int kg = kt + kk;
            int vg = bx * NT + n;
            float val = 0.f;
            if constexpr (MODE == 1) {
                int b = vg >> (3 * LOGDI), v = vg & ((1 << (3 * LOGDI)) - 1);
                int odp = v >> (2 * LOGDI), ohp = (v >> LOGDI) & (Din - 1), owp = v & (Din - 1);
                int ci = kg >> 3, t = kg & 7;
                int id = odp + pd + ((t >> 2) & 1) - 1;
                int ih = ohp + ph + ((t >> 1) & 1) - 1;
                int iw = owp + pw + (t & 1) - 1;
                if ((unsigned)id < (unsigned)Din && (unsigned)ih < (unsigned)Din &&
                    (unsigned)iw < (unsigned)Din)
                    val = x[(((size_t)(b * CIN + ci)) << (3 * LOGDI)) +
                            (id << (2 * LOGDI)) + (ih << LOGDI) + iw];
            } else if constexpr (MODE == 2) {
                int b = vg >> 15, v = vg & 32767;
                val = x[(((size_t)(b * CIN + kg)) << 15) + v];
            } else {
                int b = vg >> (3 * LOGDO), v = vg & ((1 << (3 * LOGDO)) - 1);
                int od = v >> (2 * LOGDO), oh = (v >> LOGDO) & (Do - 1), ow = v & (Do - 1);
                int ci = kg >> 6;
                int id = 2 * od - 1 + ((kg >> 4) & 3);
                int ih = 2 * oh - 1 + ((kg >> 2) & 3);
                int iw = 2 * ow - 1 + (kg & 3);
                if ((unsigned)id < (unsigned)Din && (unsigned)ih < (unsigned)Din &&
                    (unsigned)iw < (unsigned)Din) {
                    int off = (id << (2 * LOGDI)) + (ih << LOGDI) + iw;
                    if constexpr (MODE == 3) {
                        if (rawm[((size_t)b << (3 * LOGDI)) + off] > 0.5f)
                            val = x[(((size_t)(b * CIN + ci)) << (3 * LOGDI)) + off];
                    } else {
                        val = x[(((size_t)(b * CIN + ci)) << (3 * LOGDI)) + off];
                    }
                }
            }
            Bs[kk * NT + n] = val;
        }
        __syncthreads();
        // ---- compute
#pragma unroll
        for (int kk = 0; kk < KT; kk++) {
            float a[MR], bb[VR];
            if constexpr (MR == 4) {
                float4 t4 = *(const float4*)&As[kk * MT + tc * 4];
                a[0] = t4.x; a[1] = t4.y; a[2] = t4.z; a[3] = t4.w;
            } else {
                float2 t2 = *(const float2*)&As[kk * MT + tc * 2];
                a[0] = t2.x; a[1] = t2.y;
            }
            if constexpr (VR == 4) {
                float4 t4 = *(const float4*)&Bs[kk * NT + tv * 4];
                bb[0] = t4.x; bb[1] = t4.y; bb[2] = t4.z; bb[3] = t4.w;
            } else {
                float2 t2 = *(const float2*)&Bs[kk * NT + tv * 2];
                bb[0] = t2.x; bb[1] = t2.y;
            }
#pragma unroll
            for (int r = 0; r < MR; r++)
#pragma unroll
                for (int c = 0; c < VR; c++) acc[r][c] = fmaf(a[r], bb[c], acc[r][c]);
        }
    }

    // ---- epilogue
    if constexpr (MODE == 2) {
#pragma unroll
        for (int r = 0; r < MR; r++) {
            int co = by * MT + tc * MR + r;
            float bv = bias[co];
#pragma unroll
            for (int c = 0; c < VR; c++) {
                int vg = bx * NT + tv * VR + c;
                int b = vg >> 15, v = vg & 32767;
                y[(((size_t)(b * COUT + co)) << 15) + v] = acc[r][c] + bv;
            }
        }
    } else {
        float s[MR], s2[MR];
#pragma unroll
        for (int r = 0; r < MR; r++) { s[r] = 0.f; s2[r] = 0.f; }
#pragma unroll
        for (int r = 0; r < MR; r++) {
            int co = by * MT + tc * MR + r;
            float bv = bias[co];
#pragma unroll
            for (int c = 0; c < VR; c++) {
                int vg = bx * NT + tv * VR + c;
                int b, off;
                if constexpr (MODE == 1) {
                    b = vg >> (3 * LOGDI); int v = vg & ((1 << (3 * LOGDI)) - 1);
                    int odp = v >> (2 * LOGDI), ohp = (v >> LOGDI) & (Din - 1), owp = v & (Din - 1);
                    int od = 2 * odp + pd, oh = 2 * ohp + ph, ow = 2 * owp + pw;
                    off = (od << (2 * LOGDO)) + (oh << LOGDO) + ow;
                } else {
                    b = vg >> (3 * LOGDO); off = vg & ((1 << (3 * LOGDO)) - 1);
                }
                float mv = m2[((size_t)b << (3 * LOGDO)) + off];
                float yv = (acc[r][c] + bv) * mv;
                yv = yv >= 0.f ? yv : 0.01f * yv;
                y[(((size_t)(b * COUT + co)) << (3 * LOGDO)) + off] = yv;
                s[r] += yv; s2[r] += yv * yv;
            }
        }
        __syncthreads();
#pragma unroll
        for (int r = 0; r < MR; r++) {
            As[tv * MT + tc * MR + r] = s[r];
            Bs[tv * MT + tc * MR + r] = s2[r];
        }
        __syncthreads();
        if (tid < MT) {
            float S = 0.f, S2 = 0.f;
#pragma unroll
            for (int t = 0; t < 16; t++) { S += As[t * MT + tid]; S2 += Bs[t * MT + tid]; }
            int co = by * MT + tid;
            atomicAdd(&stats[co], S);
            atomicAdd(&stats[128 + co], S2);
        }
    }
}

// wrapper kernels binding static globals
__global__ __launch_bounds__(256)
void conv1_kernel(const float* feat, const float* mask, const float* w, const float* b)
{ gemm_body<3, 32, 64, 4, 32, 6, 5>(feat, mask, w, b, g_m1, g_y1, g_stats); }

__global__ __launch_bounds__(256)
void conv2_kernel(const float* w, const float* b)
{ gemm_body<0, 32, 64, 32, 64, 5, 4>(g_y1, nullptr, w, b, g_m2, g_y2, g_stats + 512); }

__global__ __launch_bounds__(256)
void conv3_kernel(const float* w, const float* b)
{ gemm_body<0, 32, 32, 64, 128, 4, 3>(g_y2, nullptr, w, b, g_m3, g_y3, g_stats + 1024); }

__global__ __launch_bounds__(256)
void conv4_kernel(const float* w, const float* b)
{ gemm_body<1, 64, 64, 128, 128, 3, 4>(g_y3, nullptr, w, b, g_mt1, g_t1, g_stats + 1536); }

__global__ __launch_bounds__(256)
void conv5_kernel(const float* w, const float* b)
{ gemm_body<1, 64, 64, 128, 64, 4, 5>(g_t1, nullptr, w, b, g_mt2, g_t2, g_stats + 2048); }

__global__ __launch_bounds__(256)
void final_kernel(const float* fw, const float* fb, float* out)
{ gemm_body<2, 32, 64, 64, 32, 5, 5>(g_t2, nullptr, fw, fb, nullptr, out, nullptr); }

// ---------------------------------------------------------------------------
// stats finalize + BN apply (unchanged)
// ---------------------------------------------------------------------------
DEV void finalize_body(float* stats, const unsigned* cnt,
                       const float* g, const float* be, int C) {
    int c = threadIdx.x;
    if (c >= C) return;
    unsigned cu = *cnt;
    float n = (float)(cu < 1u ? 1u : cu);
    float mean = stats[c] / n;
    float var = fmaxf(stats[128 + c] / n - mean * mean, 0.f);
    float rstd = rsqrtf(var + 1e-5f);
    float sc = g[c] * rstd;
    stats[256 + c] = sc;
    stats[384 + c] = be[c] - mean * sc;
}

__global__ void fin1_kernel(const float* g, const float* be) { finalize_body(g_stats + 0,    &g_cnt[0], g, be, 32); }
__global__ void fin2_kernel(const float* g, const float* be) { finalize_body(g_stats + 512,  &g_cnt[1], g, be, 64); }
__global__ void fin3_kernel(const float* g, const float* be) { finalize_body(g_stats + 1024, &g_cnt[2], g, be, 128); }
__global__ void fin4_kernel(const float* g, const float* be) { finalize_body(g_stats + 1536, &g_cnt[3], g, be, 128); }
__global__ void fin5_kernel(const float* g, const float* be) { finalize_body(g_stats + 2048, &g_cnt[4], g, be, 64); }

DEV void bn_body(float* y, const float* stats, const float* m2, int logC, int logDvox) {
    int idx = blockIdx.x * 256 + threadIdx.x;
    int v = idx & ((1 << logDvox) - 1);
    int c = (idx >> logDvox) & ((1 << logC) - 1);
    int b = idx >> (logDvox + logC);
    float mv = m2[((size_t)b << logDvox) + v];
    y[idx] = (y[idx] * stats[256 + c] + stats[384 + c]) * mv;
}

__global__ __launch_bounds__(256) void bn1_kernel() { bn_body(g_y1, g_stats + 0,    g_m1, 5, 15); }
__global__ __launch_bounds__(256) void bn2_kernel() { bn_body(g_y2, g_stats + 512,  g_m2, 6, 12); }
__global__ __launch_bounds__(256) void bn3_kernel() { bn_body(g_y3, g_stats + 1024, g_m3, 7, 9); }
__global__ __launch_bounds__(256) void bn4_kernel() { bn_body(g_t1, g_stats + 1536, g_mt1, 7, 12); }
__global__ __launch_bounds__(256) void bn5_kernel() { bn_body(g_t2, g_stats + 2048, g_mt2, 6, 15); }

// ---------------------------------------------------------------------------

extern "C" void kernel_launch(void* const* d_in, const int* in_sizes, int n_in,
                              void* d_out, int out_size, void* d_ws, size_t ws_size,
                              hipStream_t stream) {
    (void)in_sizes; (void)n_in; (void)out_size; (void)d_ws; (void)ws_size;
    const float* feat = (const float*)d_in[0];
    const float* mask = (const float*)d_in[1];
    const float* w1  = (const float*)d_in[2];
    const float* b1  = (const float*)d_in[3];
    const float* g1  = (const float*)d_in[4];
    const float* be1 = (const float*)d_in[5];
    const float* w2  = (const float*)d_in[6];
    const float* b2  = (const float*)d_in[7];
    const float* g2  = (const float*)d_in[8];
    const float* be2 = (const float*)d_in[9];
    const float* w3  = (const float*)d_in[10];
    const float* b3  = (const float*)d_in[11];
    const float* g3  = (const float*)d_in[12];
    const float* be3 = (const float*)d_in[13];
    const float* tw1 = (const float*)d_in[14];
    const float* tb1 = (const float*)d_in[15];
    const float* tg1 = (const float*)d_in[16];
    const float* tbe1= (const float*)d_in[17];
    const float* tw2 = (const float*)d_in[18];
    const float* tb2 = (const float*)d_in[19];
    const float* tg2 = (const float*)d_in[20];
    const float* tbe2= (const float*)d_in[21];
    const float* fw  = (const float*)d_in[22];
    const float* fb  = (const float*)d_in[23];

    zero_stats_kernel<<<1, 256, 0, stream>>>();

    // block 1: 4->32, 64^3 -> 32^3   (N=65536, M=32, K=256)
    mask1_kernel<<<256, 256, 0, stream>>>(mask);
    conv1_kernel<<<dim3(1024, 1), 256, 0, stream>>>(feat, mask, w1, b1);
    fin1_kernel<<<1, 128, 0, stream>>>(g1, be1);
    bn1_kernel<<<8192, 256, 0, stream>>>();

    // block 2: 32->64, 32^3 -> 16^3  (N=8192, M=64, K=2048)
    mask2_kernel<<<32, 256, 0, stream>>>();
    conv2_kernel<<<dim3(128, 2), 256, 0, stream>>>(w2, b2);
    fin2_kernel<<<1, 128, 0, stream>>>(g2, be2);
    bn2_kernel<<<2048, 256, 0, stream>>>();

    // block 3: 64->128, 16^3 -> 8^3  (N=1024, M=128, K=4096)
    mask3_kernel<<<4, 256, 0, stream>>>();
    conv3_kernel<<<dim3(32, 4), 256, 0, stream>>>(w3, b3);
    fin3_kernel<<<1, 128, 0, stream>>>(g3, be3);
    bn3_kernel<<<512, 256, 0, stream>>>();

    // up block 1: 128->128, 8^3 -> 16^3  (per-parity N=1024, K=1024)
    mask4_kernel<<<32, 256, 0, stream>>>();
    conv4_kernel<<<dim3(16, 2, 8), 256, 0, stream>>>(tw1, tb1);
    fin4_kernel<<<1, 128, 0, stream>>>(tg1, tbe1);
    bn4_kernel<<<4096, 256, 0, stream>>>();

    // up block 2: 128->64, 16^3 -> 32^3  (per-parity N=8192, K=1024)
    mask5_kernel<<<256, 256, 0, stream>>>();
    conv5_kernel<<<dim3(128, 1, 8), 256, 0, stream>>>(tw2, tb2);
    fin5_kernel<<<1, 128, 0, stream>>>(tg2, tbe2);
    bn5_kernel<<<16384, 256, 0, stream>>>();

    // final dense 1x1x1 conv 64->32 @ 32^3  (N=65536, M=32, K=64)
    final_kernel<<<dim3(1024, 1), 256, 0, stream>>>(fw, fb, (float*)d_out);
}